// Round 1
// baseline (645.104 us; speedup 1.0000x reference)
//
#include <hip/hip_runtime.h>

// ResRGCN: h=x@W1+b1; 2x {aggregate-per-(dst,rel) mean -> [h|agg]@[root;W_r]+bias, h+=relu} ; out=h@W2+b2
// Layer 3 of the reference is dead (its output is discarded) and is skipped.

#define HDIM 64
#define RREL 8
#define KCAT 576   // 64 (root/self) + 8*64 (relations)
#define NPB  16    // nodes per workgroup in MFMA kernels
#define APAD 584   // padded LDS row (584*2B = 1168B -> 2-way-bank-conflict-free)

typedef short  short8 __attribute__((ext_vector_type(8)));
typedef __bf16 bf16x8 __attribute__((ext_vector_type(8)));
typedef float  f32x4  __attribute__((ext_vector_type(4)));

static __device__ __forceinline__ unsigned short f2bf(float f) {
  unsigned int u = __builtin_bit_cast(unsigned int, f);
  u += 0x7FFFu + ((u >> 16) & 1u);
  return (unsigned short)(u >> 16);
}
static __device__ __forceinline__ float bf2f(unsigned short s) {
  unsigned int u = ((unsigned int)s) << 16;
  return __builtin_bit_cast(float, u);
}

// ---- weight prep: wt_lin1[j][k]=lin1_w[k][j]; wt_conv[l][j][k] = cat(root_l, W_r)^T in bf16
__global__ void k_prep_wt(const float* __restrict__ lin1_w, const float* __restrict__ bases,
                          const float* __restrict__ comp, const float* __restrict__ root,
                          unsigned short* __restrict__ wt_lin1, unsigned short* __restrict__ wt_conv) {
  int t = blockIdx.x * 256 + threadIdx.x;
  if (t < HDIM * HDIM) {
    int j = t >> 6, k = t & 63;
    wt_lin1[t] = f2bf(lin1_w[k * HDIM + j]);
  }
  if (t < 2 * HDIM * KCAT) {
    int l = t / (HDIM * KCAT);
    int rem = t - l * (HDIM * KCAT);
    int j = rem / KCAT;
    int k = rem - j * KCAT;
    float v;
    if (k < HDIM) {
      v = root[(l * HDIM + k) * HDIM + j];
    } else {
      int r = (k - HDIM) >> 6;
      int i = (k - HDIM) & 63;
      v = 0.f;
      #pragma unroll
      for (int b = 0; b < 4; ++b)
        v += comp[(l * RREL + r) * 4 + b] * bases[((l * 4 + b) * HDIM + i) * HDIM + j];
    }
    wt_conv[t] = f2bf(v);
  }
}

// ---- CSR-by-dst build
__global__ void k_hist(const int* __restrict__ dst, int E, unsigned int* __restrict__ deg) {
  int e = blockIdx.x * 256 + threadIdx.x;
  if (e < E) atomicAdd(&deg[dst[e]], 1u);
}

__global__ void k_scan1(const unsigned int* __restrict__ deg, unsigned int* __restrict__ off,
                        unsigned int* __restrict__ bsum, int N) {
  __shared__ unsigned int s[256];
  int t = threadIdx.x;
  int idx = blockIdx.x * 256 + t;
  unsigned int v = (idx < N) ? deg[idx] : 0u;
  s[t] = v;
  __syncthreads();
  for (int o = 1; o < 256; o <<= 1) {
    unsigned int u = (t >= o) ? s[t - o] : 0u;
    __syncthreads();
    s[t] += u;
    __syncthreads();
  }
  if (idx < N) off[idx] = s[t] - v;          // block-local exclusive
  if (t == 255) bsum[blockIdx.x] = s[t];     // block total
}

__global__ void k_scan2(unsigned int* __restrict__ bsum, unsigned int* __restrict__ off,
                        int nblk, int N, unsigned int E) {
  __shared__ unsigned int s[512];
  int t = threadIdx.x;
  unsigned int v = (t < nblk) ? bsum[t] : 0u;
  s[t] = v;
  __syncthreads();
  for (int o = 1; o < 512; o <<= 1) {
    unsigned int u = (t >= o) ? s[t - o] : 0u;
    __syncthreads();
    s[t] += u;
    __syncthreads();
  }
  if (t < nblk) bsum[t] = s[t] - v;          // exclusive block offsets
  if (t == 0) off[N] = E;
}

__global__ void k_scan3(unsigned int* __restrict__ off, const unsigned int* __restrict__ bsum, int N) {
  int idx = blockIdx.x * 256 + threadIdx.x;
  if (idx < N) off[idx] += bsum[blockIdx.x];
}

__global__ void k_scatter(const int* __restrict__ src, const int* __restrict__ dst,
                          const int* __restrict__ et, int E, const unsigned int* __restrict__ off,
                          unsigned int* __restrict__ cur, unsigned int* __restrict__ sorted) {
  int e = blockIdx.x * 256 + threadIdx.x;
  if (e < E) {
    int d = dst[e];
    unsigned int p = off[d] + atomicAdd(&cur[d], 1u);
    sorted[p] = (unsigned int)src[e] | ((unsigned int)et[e] << 17);  // src<2^17, type<8
  }
}

// ---- lin1: h = x @ W1 + b1 (MFMA over K=64), writes f32 + bf16 copies
__global__ void k_lin1(const float* __restrict__ x, const unsigned short* __restrict__ wt,
                       const float* __restrict__ bias, float* __restrict__ h,
                       unsigned short* __restrict__ hb, int N) {
  __shared__ unsigned short A[NPB][72];
  int nodebase = blockIdx.x * NPB;
  for (int i = threadIdx.x; i < NPB * HDIM; i += 256) {
    int nl = i >> 6, c = i & 63;
    int n = nodebase + nl;
    A[nl][c] = (n < N) ? f2bf(x[(size_t)n * HDIM + c]) : (unsigned short)0;
  }
  __syncthreads();
  int lane = threadIdx.x & 63, wid = threadIdx.x >> 6;
  int m16 = lane & 15, khi = lane >> 4;
  int colbase = wid * 16;
  f32x4 acc = {0.f, 0.f, 0.f, 0.f};
  #pragma unroll
  for (int kk = 0; kk < HDIM; kk += 32) {
    int k0 = kk + khi * 8;
    short8 av = *(const short8*)&A[m16][k0];
    short8 bv = *(const short8*)&wt[(colbase + m16) * HDIM + k0];
    acc = __builtin_amdgcn_mfma_f32_16x16x32_bf16(
        __builtin_bit_cast(bf16x8, av), __builtin_bit_cast(bf16x8, bv), acc, 0, 0, 0);
  }
  int j = colbase + m16;
  float bj = bias[j];
  #pragma unroll
  for (int r = 0; r < 4; ++r) {
    int nl = khi * 4 + r;
    int n = nodebase + nl;
    if (n < N) {
      float v = acc[r] + bj;
      h[(size_t)n * HDIM + j] = v;
      hb[(size_t)n * HDIM + j] = f2bf(v);
    }
  }
}

// ---- fused RGCN layer: per-node per-relation mean aggregation (wave/node, lane=channel)
//      -> LDS [16][576] bf16 -> MFMA [16x576]@[576x64] -> bias, relu, residual
__global__ void k_conv(const unsigned int* __restrict__ off, const unsigned int* __restrict__ sorted,
                       const float* __restrict__ h_in, const unsigned short* __restrict__ hb_in,
                       const unsigned short* __restrict__ wt, const float* __restrict__ bias,
                       float* __restrict__ h_out, unsigned short* __restrict__ hb_out, int N) {
  __shared__ unsigned short A[NPB][APAD];
  int nodebase = blockIdx.x * NPB;
  int lane = threadIdx.x & 63, wid = threadIdx.x >> 6;

  for (int q = 0; q < 4; ++q) {
    int nl = wid * 4 + q;
    int n = nodebase + nl;
    float aggf[RREL] = {0.f, 0.f, 0.f, 0.f, 0.f, 0.f, 0.f, 0.f};
    int cnt[RREL] = {0, 0, 0, 0, 0, 0, 0, 0};
    unsigned short hself = 0;
    if (n < N) {
      hself = hb_in[(size_t)n * HDIM + lane];
      unsigned int s0 = off[n], s1 = off[n + 1];
      for (unsigned int k = s0; k < s1; ++k) {
        unsigned int w = sorted[k];             // wave-uniform
        int s = w & 0x1FFFF;
        int t = (int)(w >> 17);
        float v = bf2f(hb_in[(size_t)s * HDIM + lane]);  // coalesced 128B gather
        #pragma unroll
        for (int r = 0; r < RREL; ++r)
          if (t == r) { aggf[r] += v; cnt[r]++; }
      }
    }
    A[nl][lane] = hself;
    #pragma unroll
    for (int r = 0; r < RREL; ++r) {
      float m = aggf[r] / fmaxf((float)cnt[r], 1.0f);
      A[nl][HDIM + r * HDIM + lane] = f2bf(m);
    }
  }
  __syncthreads();

  int m16 = lane & 15, khi = lane >> 4;
  int colbase = wid * 16;
  f32x4 acc = {0.f, 0.f, 0.f, 0.f};
  #pragma unroll
  for (int kk = 0; kk < KCAT; kk += 32) {
    int k0 = kk + khi * 8;
    short8 av = *(const short8*)&A[m16][k0];
    short8 bv = *(const short8*)&wt[(size_t)(colbase + m16) * KCAT + k0];
    acc = __builtin_amdgcn_mfma_f32_16x16x32_bf16(
        __builtin_bit_cast(bf16x8, av), __builtin_bit_cast(bf16x8, bv), acc, 0, 0, 0);
  }
  int j = colbase + m16;
  float bj = bias[j];
  #pragma unroll
  for (int r = 0; r < 4; ++r) {
    int nl = khi * 4 + r;
    int n = nodebase + nl;
    if (n < N) {
      float v = acc[r] + bj;
      float hn = h_in[(size_t)n * HDIM + j] + fmaxf(v, 0.f);
      h_out[(size_t)n * HDIM + j] = hn;
      hb_out[(size_t)n * HDIM + j] = f2bf(hn);
    }
  }
}

// ---- lin2: out = h @ W2 + b2  (OUT=2)
__global__ void k_lin2(const float* __restrict__ h, const float* __restrict__ w,
                       const float* __restrict__ b, float* __restrict__ out, int N) {
  int n = blockIdx.x * 256 + threadIdx.x;
  if (n >= N) return;
  float a0 = b[0], a1 = b[1];
  const float* hr = h + (size_t)n * HDIM;
  #pragma unroll
  for (int i = 0; i < HDIM; ++i) {
    float hv = hr[i];
    a0 += hv * w[2 * i];
    a1 += hv * w[2 * i + 1];
  }
  out[2 * n] = a0;
  out[2 * n + 1] = a1;
}

extern "C" void kernel_launch(void* const* d_in, const int* in_sizes, int n_in,
                              void* d_out, int out_size, void* d_ws, size_t ws_size,
                              hipStream_t stream) {
  const float* x      = (const float*)d_in[0];
  const int*   ei     = (const int*)d_in[1];
  const int*   et     = (const int*)d_in[2];
  const float* lin1_w = (const float*)d_in[3];
  const float* lin1_b = (const float*)d_in[4];
  const float* bases  = (const float*)d_in[5];
  const float* comp   = (const float*)d_in[6];
  const float* root   = (const float*)d_in[7];
  const float* cbias  = (const float*)d_in[8];
  const float* lin2_w = (const float*)d_in[9];
  const float* lin2_b = (const float*)d_in[10];
  float* out = (float*)d_out;

  int N = in_sizes[0] / HDIM;
  int E = in_sizes[2];
  const int* srcp = ei;
  const int* dstp = ei + E;

  char* p = (char*)d_ws;
  auto carve = [&](size_t bytes) { char* r = p; p += (bytes + 255) & ~(size_t)255; return r; };
  float*          h_a     = (float*)carve((size_t)N * HDIM * 4);
  float*          h_b     = (float*)carve((size_t)N * HDIM * 4);
  unsigned short* hb_a    = (unsigned short*)carve((size_t)N * HDIM * 2);
  unsigned short* hb_b    = (unsigned short*)carve((size_t)N * HDIM * 2);
  unsigned int*   sorted  = (unsigned int*)carve((size_t)E * 4);
  unsigned int*   deg     = (unsigned int*)carve((size_t)N * 4);
  unsigned int*   off     = (unsigned int*)carve((size_t)(N + 1) * 4);
  unsigned int*   cur     = (unsigned int*)carve((size_t)N * 4);
  unsigned int*   bsum    = (unsigned int*)carve(4096);
  unsigned short* wt_lin1 = (unsigned short*)carve((size_t)HDIM * HDIM * 2);
  unsigned short* wt_conv = (unsigned short*)carve((size_t)2 * HDIM * KCAT * 2);

  hipMemsetAsync(deg, 0, (size_t)N * 4, stream);
  hipMemsetAsync(cur, 0, (size_t)N * 4, stream);

  int eb  = (E + 255) / 256;
  int nb  = (N + 255) / 256;
  int nwg = (N + NPB - 1) / NPB;

  k_prep_wt<<<(2 * HDIM * KCAT + 255) / 256, 256, 0, stream>>>(lin1_w, bases, comp, root, wt_lin1, wt_conv);
  k_hist<<<eb, 256, 0, stream>>>(dstp, E, deg);
  k_scan1<<<nb, 256, 0, stream>>>(deg, off, bsum, N);
  k_scan2<<<1, 512, 0, stream>>>(bsum, off, nb, N, (unsigned int)E);
  k_scan3<<<nb, 256, 0, stream>>>(off, bsum, N);
  k_scatter<<<eb, 256, 0, stream>>>(srcp, dstp, et, E, off, cur, sorted);

  k_lin1<<<nwg, 256, 0, stream>>>(x, wt_lin1, lin1_b, h_a, hb_a, N);
  k_conv<<<nwg, 256, 0, stream>>>(off, sorted, h_a, hb_a, wt_conv, cbias, h_b, hb_b, N);
  k_conv<<<nwg, 256, 0, stream>>>(off, sorted, h_b, hb_b, wt_conv + HDIM * KCAT, cbias + HDIM, h_a, hb_a, N);
  k_lin2<<<nb, 256, 0, stream>>>(h_a, lin2_w, lin2_b, out, N);
}

// Round 2
// 445.859 us; speedup vs baseline: 1.4469x; 1.4469x over previous
//
#include <hip/hip_runtime.h>

// ResRGCN: h=x@W1+b1; 2x {per-(dst,rel) mean aggr -> [h|agg]@[root;W_r]+bias, h+=relu}; out=h@W2+b2
// Layer 3 of the reference is dead (output discarded) and is skipped.
// Edges are counting-sorted by key = dst*8+type, so per-(node,rel) segments are
// contiguous and counts come free from CSR offsets -> ~3 VALU/edge aggregation.

#define HDIM 64
#define RREL 8
#define KCAT 576   // 64 (root/self) + 8*64 (relations)
#define NPB  16    // nodes per workgroup in MFMA kernels
#define APAD 584   // padded LDS row

typedef short  short8 __attribute__((ext_vector_type(8)));
typedef __bf16 bf16x8 __attribute__((ext_vector_type(8)));
typedef float  f32x4  __attribute__((ext_vector_type(4)));
typedef unsigned int uint;
typedef unsigned short ushort;

static __device__ __forceinline__ ushort f2bf(float f) {
  uint u = __builtin_bit_cast(uint, f);
  u += 0x7FFFu + ((u >> 16) & 1u);
  return (ushort)(u >> 16);
}
static __device__ __forceinline__ float bf2f(ushort s) {
  uint u = ((uint)s) << 16;
  return __builtin_bit_cast(float, u);
}

// ---- weight prep: wt_lin1[j][k]=lin1_w[k][j]; wt_conv[l][j][k] = cat(root_l, W_r)^T in bf16
__global__ void k_prep_wt(const float* __restrict__ lin1_w, const float* __restrict__ bases,
                          const float* __restrict__ comp, const float* __restrict__ root,
                          ushort* __restrict__ wt_lin1, ushort* __restrict__ wt_conv) {
  int t = blockIdx.x * 256 + threadIdx.x;
  if (t < HDIM * HDIM) {
    int j = t >> 6, k = t & 63;
    wt_lin1[t] = f2bf(lin1_w[k * HDIM + j]);
  }
  if (t < 2 * HDIM * KCAT) {
    int l = t / (HDIM * KCAT);
    int rem = t - l * (HDIM * KCAT);
    int j = rem / KCAT;
    int k = rem - j * KCAT;
    float v;
    if (k < HDIM) {
      v = root[(l * HDIM + k) * HDIM + j];
    } else {
      int r = (k - HDIM) >> 6;
      int i = (k - HDIM) & 63;
      v = 0.f;
      #pragma unroll
      for (int b = 0; b < 4; ++b)
        v += comp[(l * RREL + r) * 4 + b] * bases[((l * 4 + b) * HDIM + i) * HDIM + j];
    }
    wt_conv[t] = f2bf(v);
  }
}

// ---- build CSR over keys = dst*8 + type (M = 8N bins)
__global__ void k_hist(const int* __restrict__ dst, const int* __restrict__ et, int E,
                       uint* __restrict__ deg) {
  int e = blockIdx.x * 256 + threadIdx.x;
  if (e < E) atomicAdd(&deg[dst[e] * RREL + et[e]], 1u);
}

// scan level 1: 256 threads x 4 elems = 1024/block
__global__ void k_scan1(const uint* __restrict__ deg, uint* __restrict__ off,
                        uint* __restrict__ bsum, int M) {
  __shared__ uint s[256];
  int t = threadIdx.x;
  int base = blockIdx.x * 1024 + t * 4;
  uint v0 = 0, v1 = 0, v2 = 0, v3 = 0;
  if (base + 3 < M) {
    uint4 u = *(const uint4*)(deg + base);
    v0 = u.x; v1 = u.y; v2 = u.z; v3 = u.w;
  } else {
    if (base < M)     v0 = deg[base];
    if (base + 1 < M) v1 = deg[base + 1];
    if (base + 2 < M) v2 = deg[base + 2];
    if (base + 3 < M) v3 = deg[base + 3];
  }
  uint tsum = v0 + v1 + v2 + v3;
  s[t] = tsum;
  __syncthreads();
  for (int o = 1; o < 256; o <<= 1) {
    uint u = (t >= o) ? s[t - o] : 0u;
    __syncthreads();
    s[t] += u;
    __syncthreads();
  }
  uint ex = s[t] - tsum;
  if (base < M)     off[base]     = ex;
  if (base + 1 < M) off[base + 1] = ex + v0;
  if (base + 2 < M) off[base + 2] = ex + v0 + v1;
  if (base + 3 < M) off[base + 3] = ex + v0 + v1 + v2;
  if (t == 255) bsum[blockIdx.x] = s[255];
}

// scan level 2: single block of 1024 scans the <=1024 block sums in place (exclusive)
__global__ void k_scan2(uint* __restrict__ bsum, uint* __restrict__ off, int nblk, int M, uint E) {
  __shared__ uint s[1024];
  int t = threadIdx.x;
  uint v = (t < nblk) ? bsum[t] : 0u;
  s[t] = v;
  __syncthreads();
  for (int o = 1; o < 1024; o <<= 1) {
    uint u = (t >= o) ? s[t - o] : 0u;
    __syncthreads();
    s[t] += u;
    __syncthreads();
  }
  if (t < nblk) bsum[t] = s[t] - v;
  if (t == 0) off[M] = E;
}

__global__ void k_scan3(uint* __restrict__ off, const uint* __restrict__ bsum, int M) {
  int i = blockIdx.x * 256 + threadIdx.x;
  if (i < M) off[i] += bsum[i >> 10];
}

// counting-sort scatter; atomicSub on deg leaves it zeroed (self-restoring for next call)
__global__ void k_scatter(const int* __restrict__ src, const int* __restrict__ dst,
                          const int* __restrict__ et, int E, const uint* __restrict__ off,
                          uint* __restrict__ deg, uint* __restrict__ sorted) {
  int e = blockIdx.x * 256 + threadIdx.x;
  if (e < E) {
    int key = dst[e] * RREL + et[e];
    uint p = off[key] + atomicSub(&deg[key], 1u) - 1u;
    sorted[p] = (uint)src[e];
  }
}

// ---- lin1: h = x @ W1 + b1 (MFMA over K=64), writes f32 + bf16 copies
__global__ void k_lin1(const float* __restrict__ x, const ushort* __restrict__ wt,
                       const float* __restrict__ bias, float* __restrict__ h,
                       ushort* __restrict__ hb, int N) {
  __shared__ ushort A[NPB][72];
  int nodebase = blockIdx.x * NPB;
  for (int i = threadIdx.x; i < NPB * HDIM; i += 256) {
    int nl = i >> 6, c = i & 63;
    int n = nodebase + nl;
    A[nl][c] = (n < N) ? f2bf(x[(size_t)n * HDIM + c]) : (ushort)0;
  }
  __syncthreads();
  int lane = threadIdx.x & 63, wid = threadIdx.x >> 6;
  int m16 = lane & 15, khi = lane >> 4;
  int colbase = wid * 16;
  f32x4 acc = {0.f, 0.f, 0.f, 0.f};
  #pragma unroll
  for (int kk = 0; kk < HDIM; kk += 32) {
    int k0 = kk + khi * 8;
    short8 av = *(const short8*)&A[m16][k0];
    short8 bv = *(const short8*)&wt[(colbase + m16) * HDIM + k0];
    acc = __builtin_amdgcn_mfma_f32_16x16x32_bf16(
        __builtin_bit_cast(bf16x8, av), __builtin_bit_cast(bf16x8, bv), acc, 0, 0, 0);
  }
  int j = colbase + m16;
  float bj = bias[j];
  #pragma unroll
  for (int r = 0; r < 4; ++r) {
    int nl = khi * 4 + r;
    int n = nodebase + nl;
    if (n < N) {
      float v = acc[r] + bj;
      h[(size_t)n * HDIM + j] = v;
      hb[(size_t)n * HDIM + j] = f2bf(v);
    }
  }
}

// ---- fused RGCN layer: per-(node,rel) segment mean (wave/node, lane=channel)
//      -> LDS [16][576] bf16 -> MFMA [16x576]@[576x64] -> bias, relu, residual
__global__ void k_conv(const uint* __restrict__ off8, const uint* __restrict__ sorted,
                       const float* __restrict__ h_in, const ushort* __restrict__ hb_in,
                       const ushort* __restrict__ wt, const float* __restrict__ bias,
                       float* __restrict__ h_out, ushort* __restrict__ hb_out, int N) {
  __shared__ ushort A[NPB][APAD];
  int nodebase = blockIdx.x * NPB;
  int lane = threadIdx.x & 63, wid = threadIdx.x >> 6;
  const ushort* hlane = hb_in + lane;

  for (int q = 0; q < 4; ++q) {
    int nl = wid * 4 + q;
    int n = nodebase + nl;
    if (n < N) {
      A[nl][lane] = hb_in[(uint)n * HDIM + lane];
      const uint* ob = off8 + (uint)n * RREL;
      uint4 b0 = *(const uint4*)ob;
      uint4 b1 = *(const uint4*)(ob + 4);
      uint blast = ob[8];
      uint bnds[9];
      bnds[0] = __builtin_amdgcn_readfirstlane(b0.x);
      bnds[1] = __builtin_amdgcn_readfirstlane(b0.y);
      bnds[2] = __builtin_amdgcn_readfirstlane(b0.z);
      bnds[3] = __builtin_amdgcn_readfirstlane(b0.w);
      bnds[4] = __builtin_amdgcn_readfirstlane(b1.x);
      bnds[5] = __builtin_amdgcn_readfirstlane(b1.y);
      bnds[6] = __builtin_amdgcn_readfirstlane(b1.z);
      bnds[7] = __builtin_amdgcn_readfirstlane(b1.w);
      bnds[8] = __builtin_amdgcn_readfirstlane(blast);
      #pragma unroll
      for (int r = 0; r < RREL; ++r) {
        uint s0 = bnds[r], s1 = bnds[r + 1];
        float acc = 0.f;
        uint k = s0;
        for (; k + 2 <= s1; k += 2) {
          uint sa = sorted[k];
          uint sb = sorted[k + 1];
          float va = bf2f(hlane[sa << 6]);
          float vb = bf2f(hlane[sb << 6]);
          acc += va;
          acc += vb;
        }
        if (k < s1) acc += bf2f(hlane[sorted[k] << 6]);
        float m = acc * __frcp_rn(fmaxf((float)(s1 - s0), 1.0f));
        A[nl][HDIM + r * HDIM + lane] = f2bf(m);
      }
    } else {
      A[nl][lane] = 0;
      #pragma unroll
      for (int r = 0; r < RREL; ++r) A[nl][HDIM + r * HDIM + lane] = 0;
    }
  }
  __syncthreads();

  int m16 = lane & 15, khi = lane >> 4;
  int colbase = wid * 16;
  f32x4 acc = {0.f, 0.f, 0.f, 0.f};
  #pragma unroll
  for (int kk = 0; kk < KCAT; kk += 32) {
    int k0 = kk + khi * 8;
    short8 av = *(const short8*)&A[m16][k0];
    short8 bv = *(const short8*)&wt[(uint)(colbase + m16) * KCAT + k0];
    acc = __builtin_amdgcn_mfma_f32_16x16x32_bf16(
        __builtin_bit_cast(bf16x8, av), __builtin_bit_cast(bf16x8, bv), acc, 0, 0, 0);
  }
  int j = colbase + m16;
  float bj = bias[j];
  #pragma unroll
  for (int r = 0; r < 4; ++r) {
    int nl = khi * 4 + r;
    int n = nodebase + nl;
    if (n < N) {
      float v = acc[r] + bj;
      float hn = h_in[(uint)n * HDIM + j] + fmaxf(v, 0.f);
      h_out[(uint)n * HDIM + j] = hn;
      hb_out[(uint)n * HDIM + j] = f2bf(hn);
    }
  }
}

// ---- lin2: out = h @ W2 + b2  (OUT=2)
__global__ void k_lin2(const float* __restrict__ h, const float* __restrict__ w,
                       const float* __restrict__ b, float* __restrict__ out, int N) {
  int n = blockIdx.x * 256 + threadIdx.x;
  if (n >= N) return;
  float a0 = b[0], a1 = b[1];
  const float* hr = h + (size_t)n * HDIM;
  #pragma unroll
  for (int i = 0; i < HDIM; ++i) {
    float hv = hr[i];
    a0 += hv * w[2 * i];
    a1 += hv * w[2 * i + 1];
  }
  out[2 * n] = a0;
  out[2 * n + 1] = a1;
}

extern "C" void kernel_launch(void* const* d_in, const int* in_sizes, int n_in,
                              void* d_out, int out_size, void* d_ws, size_t ws_size,
                              hipStream_t stream) {
  const float* x      = (const float*)d_in[0];
  const int*   ei     = (const int*)d_in[1];
  const int*   et     = (const int*)d_in[2];
  const float* lin1_w = (const float*)d_in[3];
  const float* lin1_b = (const float*)d_in[4];
  const float* bases  = (const float*)d_in[5];
  const float* comp   = (const float*)d_in[6];
  const float* root   = (const float*)d_in[7];
  const float* cbias  = (const float*)d_in[8];
  const float* lin2_w = (const float*)d_in[9];
  const float* lin2_b = (const float*)d_in[10];
  float* out = (float*)d_out;

  int N = in_sizes[0] / HDIM;
  int E = in_sizes[2];
  int M = N * RREL;                 // CSR bins
  const int* srcp = ei;
  const int* dstp = ei + E;

  char* p = (char*)d_ws;
  auto carve = [&](size_t bytes) { char* r = p; p += (bytes + 255) & ~(size_t)255; return r; };
  float*  h_a     = (float*)carve((size_t)N * HDIM * 4);
  float*  h_b     = (float*)carve((size_t)N * HDIM * 4);
  ushort* hb_a    = (ushort*)carve((size_t)N * HDIM * 2);
  ushort* hb_b    = (ushort*)carve((size_t)N * HDIM * 2);
  uint*   sorted  = (uint*)carve((size_t)E * 4);
  uint*   deg8    = (uint*)carve((size_t)M * 4);
  uint*   off8    = (uint*)carve((size_t)(M + 1) * 4);
  uint*   bsum    = (uint*)carve(4096);
  ushort* wt_lin1 = (ushort*)carve((size_t)HDIM * HDIM * 2);
  ushort* wt_conv = (ushort*)carve((size_t)2 * HDIM * KCAT * 2);

  hipMemsetAsync(deg8, 0, (size_t)M * 4, stream);

  int eb    = (E + 255) / 256;
  int nb    = (N + 255) / 256;
  int nwg   = (N + NPB - 1) / NPB;
  int nblk1 = (M + 1023) / 1024;   // <= 1024 required (N <= 131072)
  int mb    = (M + 255) / 256;

  k_prep_wt<<<(2 * HDIM * KCAT + 255) / 256, 256, 0, stream>>>(lin1_w, bases, comp, root, wt_lin1, wt_conv);
  k_hist<<<eb, 256, 0, stream>>>(dstp, et, E, deg8);
  k_scan1<<<nblk1, 256, 0, stream>>>(deg8, off8, bsum, M);
  k_scan2<<<1, 1024, 0, stream>>>(bsum, off8, nblk1, M, (uint)E);
  k_scan3<<<mb, 256, 0, stream>>>(off8, bsum, M);
  k_scatter<<<eb, 256, 0, stream>>>(srcp, dstp, et, E, off8, deg8, sorted);

  k_lin1<<<nwg, 256, 0, stream>>>(x, wt_lin1, lin1_b, h_a, hb_a, N);
  k_conv<<<nwg, 256, 0, stream>>>(off8, sorted, h_a, hb_a, wt_conv, cbias, h_b, hb_b, N);
  k_conv<<<nwg, 256, 0, stream>>>(off8, sorted, h_b, hb_b, wt_conv + HDIM * KCAT, cbias + HDIM, h_a, hb_a, N);
  k_lin2<<<nb, 256, 0, stream>>>(h_a, lin2_w, lin2_b, out, N);
}